// Round 5
// baseline (88.285 us; speedup 1.0000x reference)
//
#include <hip/hip_runtime.h>
#include <hip/hip_bf16.h>

// Problem constants (fixed shapes from setup_inputs)
constexpr int NPTS = 16384;   // points per batch
constexpr int NCTR = 2048;    // centers per batch
constexpr int NCH  = 64;      // feature channels
constexpr int KK   = 32;      // neighbors per center
constexpr int NB   = 2;       // batches
// radius^2: reference compares d2 < fp32(0.04) (python double 0.2*0.2 -> f32)
#define R2 0.04f

// -------- Kernel A (prep): transpose feats + pack points --------
// blocks [0,512):   transpose features (b,64,16384) -> (b,16384,64) into ws
// blocks [512,544): pack points -> float4 (x,y,z,p2) into ws
// p2 computed ONCE here with the exact R1-verified formula (contract off),
// so the scan's d2 stays bit-identical to numpy.
__global__ __launch_bounds__(256) void prep_kernel(
    const float* __restrict__ points,   // (2,16384,3)
    const float* __restrict__ feats,    // (2,64,16384)
    float* __restrict__ featsT,         // ws: (2,16384,64)
    float4* __restrict__ packed)        // ws: (2*16384) {x,y,z,p2}
{
#pragma clang fp contract(off)
    __shared__ float tile[64][65];      // +1 pad: conflict-free transpose

    if (blockIdx.x < 512) {
        // ---------------- transpose ----------------
        const int b  = blockIdx.x >> 8;
        const int n0 = (blockIdx.x & 255) * 64;
        const int t  = threadIdx.x;
        const int nl = t & 63;
        const int q  = t >> 6;

        const float* fb = feats + (size_t)b * NCH * NPTS;
#pragma unroll
        for (int r = 0; r < 16; ++r) {
            int c = r * 4 + q;
            tile[c][nl] = fb[(size_t)c * NPTS + n0 + nl];
        }
        __syncthreads();
        float* ftb = featsT + ((size_t)b * NPTS + n0) * NCH;
#pragma unroll
        for (int r = 0; r < 16; ++r) {
            int n = r * 4 + q;
            ftb[(size_t)n * NCH + nl] = tile[nl][n];   // 2-way max (free)
        }
        return;
    }

    // ---------------- pack: 32 blocks x 256 thr x 4 pts ----------------
    const int tid = (blockIdx.x - 512) * 256 + threadIdx.x;  // 0..8191
#pragma unroll
    for (int s = 0; s < 4; ++s) {
        const int i = tid + s * 8192;                        // 0..32767 (b*NPTS+n)
        const float x = points[3 * i + 0];
        const float y = points[3 * i + 1];
        const float z = points[3 * i + 2];
        const float p2 = (x * x + y * y) + z * z;            // exact R1 formula
        packed[i] = make_float4(x, y, z, p2);
    }
}

// -------- Kernel B: fused query+group, ONE BLOCK (4 waves) per center ----
// R4's one-wave-per-center left tail waves with 32 serial chunk-iters and a
// single-wave epilogue. Here 4 waves scan 2048 pts/iter in parallel (exact
// index order kept via LDS wave-prefix), cutting tail serial depth ~2.5x,
// and the gather/write epilogue gets 4x the lanes. ~9.5 KB LDS/block.
__global__ __launch_bounds__(256) void query_group(
    const float4* __restrict__ packed,  // (2,16384) {x,y,z,p2}
    const float* __restrict__ centers,  // (2,2048,3)
    const float* __restrict__ featsT,   // (2,16384,64)
    float* __restrict__ out_xyz,        // (2,3,2048,32)
    float* __restrict__ out_feat)       // (2,64,2048,32)
{
#pragma clang fp contract(off)          // keep numpy-exact d2 (absmax=0 since R1)
    __shared__ int   lidx[4][KK];       // per-wave local hit lists (this iter)
    __shared__ int   scnt[4];           // per-wave hit counts (this iter)
    __shared__ int   idxs[KK];          // the global first-32 list
    __shared__ float sf[KK][68];        // gather staging; 16B-aligned rows

    const int wave = threadIdx.x >> 6;
    const int lane = threadIdx.x & 63;
    const int cg   = blockIdx.x;        // 0..4095 (block-uniform!)
    const int b    = cg >> 11;
    const int g    = cg & (NCTR - 1);

    const float4* pk = packed + (size_t)b * NPTS;
    const float* cc = centers + (size_t)cg * 3;    // uniform -> s_load
    const float cx = cc[0], cy = cc[1], cz = cc[2];
    const float c2 = (cx * cx + cy * cy) + cz * cz;

    // ---- cooperative scan: wave w owns [base+512w, base+512w+512) ----
    const int off0 = wave * 512 + lane;
    float4 cur[8], nxt[8];
#pragma unroll
    for (int j = 0; j < 8; ++j) cur[j] = pk[off0 + j * 64];

    int gcnt = 0;
    for (int base = 0; base < NPTS; base += 2048) {
        const int nbb = (base + 2048 < NPTS) ? base + 2048 : 0;
#pragma unroll
        for (int j = 0; j < 8; ++j) nxt[j] = pk[nbb + off0 + j * 64];

        // wave-local ordered ballots over 512 pts
        int lc = 0;
#pragma unroll
        for (int j = 0; j < 8; ++j) {
            const float4 v = cur[j];
            const float cp = (cx * v.x + cy * v.y) + cz * v.z;
            const float d2 = (c2 + v.w) - 2.0f * cp;
            const bool hit = d2 < R2;
            const unsigned long long m = __ballot(hit);
            if (hit) {
                const int slot = lc + __popcll(m & ((1ull << lane) - 1ull));
                if (slot < KK) lidx[wave][slot] = base + off0 + j * 64;
            }
            lc += (int)__popcll(m);
        }
        if (lane == 0) scnt[wave] = lc;
        __syncthreads();

        // 4-entry prefix (uniform within wave) + merge into global list
        int pre = 0, tot = 0;
#pragma unroll
        for (int w = 0; w < 4; ++w) {
            const int c = scnt[w];
            tot += c;
            if (w < wave) pre += c;
        }
        const int nl = lc < KK ? lc : KK;
        if (lane < nl) {
            const int gs = gcnt + pre + lane;   // slot>=KK locally => gs>=KK
            if (gs < KK) idxs[gs] = lidx[wave][lane];
        }
        gcnt += tot;                            // block-uniform
        __syncthreads();                        // scnt/lidx reuse + idxs vis
        if (gcnt >= KK) break;                  // block-uniform
#pragma unroll
        for (int j = 0; j < 8; ++j) cur[j] = nxt[j];
    }
    __syncthreads();

    // ---- pad + grouped_xyz (one thread per k) ----
    const int cpd = gcnt < KK ? gcnt : KK;
    const int first = (gcnt > 0) ? idxs[0] : 0;
    if (threadIdx.x < KK) {
        const int id = (threadIdx.x < cpd) ? idxs[threadIdx.x] : first;
        idxs[threadIdx.x] = id;
        const float4 v = pk[id];
        const size_t ob = (((size_t)b * 3 + 0) * NCTR + g) * KK + threadIdx.x;
        out_xyz[ob + (size_t)0 * NCTR * KK] = (v.x - cx) / 0.2f;
        out_xyz[ob + (size_t)1 * NCTR * KK] = (v.y - cy) / 0.2f;
        out_xyz[ob + (size_t)2 * NCTR * KK] = (v.z - cz) / 0.2f;
    }
    __syncthreads();

    // ---- gather: wave w loads rows 8w..8w+7 (2 b128 instrs/wave) ----
    const int li = lane & 15, r = lane >> 4;
    const float* ftb = featsT + (size_t)b * NPTS * NCH;
#pragma unroll
    for (int i = 0; i < 2; ++i) {
        const int k = wave * 8 + i * 4 + r;
        const float4 v = *((const float4*)(ftb + (size_t)idxs[k] * NCH) + li);
        *(float4*)&sf[k][4 * li] = v;
    }
    __syncthreads();

    // ---- write: thread owns k-quad [4kq,4kq+4) of channel c; 2 passes ----
    const int kq = threadIdx.x & 7;
    const int c0 = threadIdx.x >> 3;        // 0..31
    const size_t ob = ((size_t)b * NCH * NCTR + g) * KK;
#pragma unroll
    for (int p = 0; p < 2; ++p) {
        const int c = c0 + 32 * p;
        float4 v;
        v.x = sf[4 * kq + 0][c];            // 4-way LDS conflict: small epilogue
        v.y = sf[4 * kq + 1][c];
        v.z = sf[4 * kq + 2][c];
        v.w = sf[4 * kq + 3][c];
        *(float4*)(out_feat + ob + (size_t)c * NCTR * KK + 4 * kq) = v;
    }
}

// -------- Fallback: R2 fused kernel (used only if ws is too small) --------
__global__ __launch_bounds__(256) void ballquery_group(
    const float* __restrict__ points, const float* __restrict__ centers,
    const float* __restrict__ feats, float* __restrict__ out_xyz,
    float* __restrict__ out_feat)
{
#pragma clang fp contract(off)
    __shared__ int   s_idx[4][KK];
    __shared__ float s_f[4][KK][65];
    const int wave = threadIdx.x >> 6, lane = threadIdx.x & 63;
    const int cg = blockIdx.x * 4 + wave;
    const int b = cg >> 11, g = cg & (NCTR - 1);
    const float* pb = points + (size_t)b * NPTS * 3;
    const float* cc = centers + (size_t)cg * 3;
    const float cx = cc[0], cy = cc[1], cz = cc[2];
    const float c2 = (cx * cx + cy * cy) + cz * cz;
    int* idxs = s_idx[wave];
    int cnt = 0;
    for (int base = 0; base < NPTS; base += 64) {
        const int i = base + lane;
        const float px = pb[i * 3 + 0], py = pb[i * 3 + 1], pz = pb[i * 3 + 2];
        const float p2 = (px * px + py * py) + pz * pz;
        const float cp = (cx * px + cy * py) + cz * pz;
        const float d2 = (c2 + p2) - 2.0f * cp;
        const bool hit = d2 < R2;
        const unsigned long long m = __ballot(hit);
        if (hit) {
            const int slot = cnt + __popcll(m & ((1ull << lane) - 1ull));
            if (slot < KK) idxs[slot] = i;
        }
        cnt += (int)__popcll(m);
        if (cnt >= KK) break;
    }
    __syncthreads();
    const int cpd = cnt < KK ? cnt : KK;
    const int first = (cnt > 0) ? idxs[0] : 0;
    if (lane < KK) idxs[lane] = (lane < cpd) ? idxs[lane] : first;
    __syncthreads();
    if (lane < KK) {
        const int id = idxs[lane];
        const float px = pb[id * 3 + 0], py = pb[id * 3 + 1], pz = pb[id * 3 + 2];
        const size_t ob = (((size_t)b * 3 + 0) * NCTR + g) * KK + lane;
        out_xyz[ob + (size_t)0 * NCTR * KK] = (px - cx) / 0.2f;
        out_xyz[ob + (size_t)1 * NCTR * KK] = (py - cy) / 0.2f;
        out_xyz[ob + (size_t)2 * NCTR * KK] = (pz - cz) / 0.2f;
    }
    float (*sf)[65] = s_f[wave];
    const float* fb = feats + (size_t)b * NCH * NPTS;
    for (int k = 0; k < KK; ++k) {
        const int id = idxs[k];
        sf[k][lane] = fb[(size_t)lane * NPTS + id];
    }
    __syncthreads();
    const int k = lane & 31, ch = lane >> 5;
    const size_t ob = ((size_t)b * NCH * NCTR + g) * KK;
#pragma unroll
    for (int cc2 = 0; cc2 < 32; ++cc2) {
        const int c = cc2 * 2 + ch;
        out_feat[ob + (size_t)c * NCTR * KK + k] = sf[k][c];
    }
}

extern "C" void kernel_launch(void* const* d_in, const int* in_sizes, int n_in,
                              void* d_out, int out_size, void* d_ws, size_t ws_size,
                              hipStream_t stream) {
    const float* points  = (const float*)d_in[0];   // (2,16384,3)
    const float* centers = (const float*)d_in[1];   // (2,2048,3)
    const float* feats   = (const float*)d_in[2];   // (2,64,16384)

    float* out      = (float*)d_out;
    float* out_xyz  = out;                                    // (2,3,2048,32)
    float* out_feat = out + (size_t)NB * 3 * NCTR * KK;       // (2,64,2048,32)

    const size_t ftBytes = (size_t)NB * NPTS * NCH * sizeof(float);   // 8 MB
    const size_t pkBytes = (size_t)NB * NPTS * 4 * sizeof(float);     // 512 KB

    if (ws_size >= ftBytes + pkBytes) {
        float*  featsT = (float*)d_ws;
        float4* packed = (float4*)((char*)d_ws + ftBytes);
        // blocks [0,512): transpose; [512,544): pack points
        prep_kernel<<<544, 256, 0, stream>>>(points, feats, featsT, packed);
        // one block per center
        query_group<<<NB * NCTR, 256, 0, stream>>>(
            packed, centers, featsT, out_xyz, out_feat);
    } else {
        ballquery_group<<<(NB * NCTR) / 4, 256, 0, stream>>>(
            points, centers, feats, out_xyz, out_feat);
    }
}

// Round 6
// 86.645 us; speedup vs baseline: 1.0189x; 1.0189x over previous
//
#include <hip/hip_runtime.h>
#include <hip/hip_bf16.h>

// Problem constants (fixed shapes from setup_inputs)
constexpr int NPTS = 16384;   // points per batch
constexpr int NCTR = 2048;    // centers per batch
constexpr int NCH  = 64;      // feature channels
constexpr int KK   = 32;      // neighbors per center
constexpr int NB   = 2;       // batches
// radius^2: reference compares d2 < fp32(0.04) (python double 0.2*0.2 -> f32)
#define R2 0.04f

// -------- Kernel A (prep): transpose feats + pack points --------
// blocks [0,512):   transpose features (b,64,16384) -> (b,16384,64) into ws
// blocks [512,544): pack points -> float4 (2x,2y,2z,p2) into ws
// Coords stored DOUBLED: d2 = (c2+p2) - ((2x)cx+(2y)cy+(2z)cz) is bit-equal
// to (c2+p2) - 2*cp because fp rounding commutes with *2^k. p2 uses the
// exact R1-verified formula (contract off) -> selection bit-identical.
__global__ __launch_bounds__(256) void prep_kernel(
    const float* __restrict__ points,   // (2,16384,3)
    const float* __restrict__ feats,    // (2,64,16384)
    float* __restrict__ featsT,         // ws: (2,16384,64)
    float4* __restrict__ packed)        // ws: (2*16384) {2x,2y,2z,p2}
{
#pragma clang fp contract(off)
    __shared__ float tile[64][65];      // +1 pad: conflict-free transpose

    if (blockIdx.x < 512) {
        // ---------------- transpose (cross-wave tile: barrier REQUIRED) ----
        const int b  = blockIdx.x >> 8;
        const int n0 = (blockIdx.x & 255) * 64;
        const int t  = threadIdx.x;
        const int nl = t & 63;
        const int q  = t >> 6;

        const float* fb = feats + (size_t)b * NCH * NPTS;
#pragma unroll
        for (int r = 0; r < 16; ++r) {
            int c = r * 4 + q;
            tile[c][nl] = fb[(size_t)c * NPTS + n0 + nl];
        }
        __syncthreads();
        float* ftb = featsT + ((size_t)b * NPTS + n0) * NCH;
#pragma unroll
        for (int r = 0; r < 16; ++r) {
            int n = r * 4 + q;
            ftb[(size_t)n * NCH + nl] = tile[nl][n];   // 2-way max (free)
        }
        return;
    }

    // ---------------- pack: 32 blocks x 256 thr x 4 pts ----------------
    const int tid = (blockIdx.x - 512) * 256 + threadIdx.x;  // 0..8191
#pragma unroll
    for (int s = 0; s < 4; ++s) {
        const int i = tid + s * 8192;                        // 0..32767 (b*NPTS+n)
        const float x = points[3 * i + 0];
        const float y = points[3 * i + 1];
        const float z = points[3 * i + 2];
        const float p2 = (x * x + y * y) + z * z;            // exact R1 formula
        packed[i] = make_float4(x + x, y + y, z + z, p2);    // doubled (exact)
    }
}

// -------- Kernel B: fused query+group, one wave per center, ZERO barriers --
// R4 had per-wave LDS but block-wide __syncthreads: a corner-center wave
// (full 16k scan) stalled its 3 sibling waves at every barrier. All LDS here
// is wave-private; same-wave DS ops are in-order and the compiler inserts
// lgkmcnt waits, so no barriers are needed -> waves fully independent.
// LDS 17.9 KB/block (two 16-row gather passes).
__global__ __launch_bounds__(256, 4) void query_group(
    const float4* __restrict__ packed,  // (2,16384) {2x,2y,2z,p2}
    const float* __restrict__ centers,  // (2,2048,3)
    const float* __restrict__ featsT,   // (2,16384,64)
    float* __restrict__ out_xyz,        // (2,3,2048,32)
    float* __restrict__ out_feat)       // (2,64,2048,32)
{
#pragma clang fp contract(off)          // keep numpy-exact d2 (absmax=0 since R1)
    __shared__ int   s_idx[4][KK];      // per-wave
    __shared__ float s_f[4][16][68];    // per-wave; 16 rows/pass, 16B-aligned

    const int wave = threadIdx.x >> 6;
    const int lane = threadIdx.x & 63;
    const int cg   = blockIdx.x * 4 + wave;   // 0..4095
    const int b    = cg >> 11;
    const int g    = cg & (NCTR - 1);

    const float4* pk = packed + (size_t)b * NPTS;
    const float* cc = centers + (size_t)cg * 3;
    const float cx = cc[0], cy = cc[1], cz = cc[2];
    const float c2 = (cx * cx + cy * cy) + cz * cz;

    int* idxs = s_idx[wave];

    // ---- chunked ballot scan: 512 pts/chunk, next chunk prefetched ----
    float4 cur[8], nxt[8];
#pragma unroll
    for (int j = 0; j < 8; ++j) cur[j] = pk[j * 64 + lane];
    int cnt = 0;
    for (int base = 0; base < NPTS; base += 512) {
        const int nbb = (base + 512 < NPTS) ? base + 512 : 0;
#pragma unroll
        for (int j = 0; j < 8; ++j) nxt[j] = pk[nbb + j * 64 + lane];
#pragma unroll
        for (int j = 0; j < 8; ++j) {
            const float4 v = cur[j];
            const float cp2 = (cx * v.x + cy * v.y) + cz * v.z;  // == 2*cp exact
            const float d2 = (c2 + v.w) - cp2;
            const bool hit = d2 < R2;
            const unsigned long long m = __ballot(hit);
            if (hit) {
                const int slot = cnt + __popcll(m & ((1ull << lane) - 1ull));
                if (slot < KK) idxs[slot] = base + j * 64 + lane;
            }
            cnt += (int)__popcll(m);
        }
        if (cnt >= KK) break;                 // wave-uniform (cnt from ballot)
#pragma unroll
        for (int j = 0; j < 8; ++j) cur[j] = nxt[j];
    }
    // NO __syncthreads: idxs is wave-private; same-wave DS ordering suffices.

    // ---- pad + grouped_xyz ----
    const int cpd = cnt < KK ? cnt : KK;
    const int first = (cnt > 0) ? idxs[0] : 0;
    if (lane < KK) {
        const int id = (lane < cpd) ? idxs[lane] : first;
        idxs[lane] = id;
        const float4 v = pk[id];
        const float px = 0.5f * v.x, py = 0.5f * v.y, pz = 0.5f * v.z;  // exact
        const size_t ob = (((size_t)b * 3 + 0) * NCTR + g) * KK + lane;
        out_xyz[ob + (size_t)0 * NCTR * KK] = (px - cx) / 0.2f;
        out_xyz[ob + (size_t)1 * NCTR * KK] = (py - cy) / 0.2f;
        out_xyz[ob + (size_t)2 * NCTR * KK] = (pz - cz) / 0.2f;
    }

    // ---- gather+write: two 16-row passes through wave-private LDS ----
    float (*sf)[68] = s_f[wave];
    const int li = lane & 15, r = lane >> 4;      // gather mapping
    const int kqL = lane & 3, c0 = lane >> 2;     // write mapping (c0: 0..15)
    const float* ftb = featsT + (size_t)b * NPTS * NCH;
    const size_t ob = ((size_t)b * NCH * NCTR + g) * KK;
#pragma unroll
    for (int pass = 0; pass < 2; ++pass) {
        const int k0 = pass * 16;
        // load 16 rows: 4 rows per b128 instr
#pragma unroll
        for (int i = 0; i < 4; ++i) {
            const int kl = i * 4 + r;             // local row 0..15
            const float4 v = *((const float4*)(ftb + (size_t)idxs[k0 + kl] * NCH) + li);
            *(float4*)&sf[kl][4 * li] = v;
        }
        // write: lane owns local k-quad [4kqL,4kqL+4) of channel c; 4 passes
#pragma unroll
        for (int p = 0; p < 4; ++p) {
            const int c = c0 + 16 * p;
            float4 w;
            w.x = sf[4 * kqL + 0][c];             // 2-way LDS aliasing: free
            w.y = sf[4 * kqL + 1][c];
            w.z = sf[4 * kqL + 2][c];
            w.w = sf[4 * kqL + 3][c];
            // 4 lanes cover 64B line of (c,g) row at offset k0: full lines
            *(float4*)(out_feat + ob + (size_t)c * NCTR * KK + k0 + 4 * kqL) = w;
        }
        // pass1 LDS writes can't pass pass0 reads: same-wave DS is in-order.
    }
}

// -------- Fallback: R2 fused kernel (used only if ws is too small) --------
__global__ __launch_bounds__(256) void ballquery_group(
    const float* __restrict__ points, const float* __restrict__ centers,
    const float* __restrict__ feats, float* __restrict__ out_xyz,
    float* __restrict__ out_feat)
{
#pragma clang fp contract(off)
    __shared__ int   s_idx[4][KK];
    __shared__ float s_f[4][KK][65];
    const int wave = threadIdx.x >> 6, lane = threadIdx.x & 63;
    const int cg = blockIdx.x * 4 + wave;
    const int b = cg >> 11, g = cg & (NCTR - 1);
    const float* pb = points + (size_t)b * NPTS * 3;
    const float* cc = centers + (size_t)cg * 3;
    const float cx = cc[0], cy = cc[1], cz = cc[2];
    const float c2 = (cx * cx + cy * cy) + cz * cz;
    int* idxs = s_idx[wave];
    int cnt = 0;
    for (int base = 0; base < NPTS; base += 64) {
        const int i = base + lane;
        const float px = pb[i * 3 + 0], py = pb[i * 3 + 1], pz = pb[i * 3 + 2];
        const float p2 = (px * px + py * py) + pz * pz;
        const float cp = (cx * px + cy * py) + cz * pz;
        const float d2 = (c2 + p2) - 2.0f * cp;
        const bool hit = d2 < R2;
        const unsigned long long m = __ballot(hit);
        if (hit) {
            const int slot = cnt + __popcll(m & ((1ull << lane) - 1ull));
            if (slot < KK) idxs[slot] = i;
        }
        cnt += (int)__popcll(m);
        if (cnt >= KK) break;
    }
    __syncthreads();
    const int cpd = cnt < KK ? cnt : KK;
    const int first = (cnt > 0) ? idxs[0] : 0;
    if (lane < KK) idxs[lane] = (lane < cpd) ? idxs[lane] : first;
    __syncthreads();
    if (lane < KK) {
        const int id = idxs[lane];
        const float px = pb[id * 3 + 0], py = pb[id * 3 + 1], pz = pb[id * 3 + 2];
        const size_t ob = (((size_t)b * 3 + 0) * NCTR + g) * KK + lane;
        out_xyz[ob + (size_t)0 * NCTR * KK] = (px - cx) / 0.2f;
        out_xyz[ob + (size_t)1 * NCTR * KK] = (py - cy) / 0.2f;
        out_xyz[ob + (size_t)2 * NCTR * KK] = (pz - cz) / 0.2f;
    }
    float (*sf)[65] = s_f[wave];
    const float* fb = feats + (size_t)b * NCH * NPTS;
    for (int k = 0; k < KK; ++k) {
        const int id = idxs[k];
        sf[k][lane] = fb[(size_t)lane * NPTS + id];
    }
    __syncthreads();
    const int k = lane & 31, ch = lane >> 5;
    const size_t ob = ((size_t)b * NCH * NCTR + g) * KK;
#pragma unroll
    for (int cc2 = 0; cc2 < 32; ++cc2) {
        const int c = cc2 * 2 + ch;
        out_feat[ob + (size_t)c * NCTR * KK + k] = sf[k][c];
    }
}

extern "C" void kernel_launch(void* const* d_in, const int* in_sizes, int n_in,
                              void* d_out, int out_size, void* d_ws, size_t ws_size,
                              hipStream_t stream) {
    const float* points  = (const float*)d_in[0];   // (2,16384,3)
    const float* centers = (const float*)d_in[1];   // (2,2048,3)
    const float* feats   = (const float*)d_in[2];   // (2,64,16384)

    float* out      = (float*)d_out;
    float* out_xyz  = out;                                    // (2,3,2048,32)
    float* out_feat = out + (size_t)NB * 3 * NCTR * KK;       // (2,64,2048,32)

    const size_t ftBytes = (size_t)NB * NPTS * NCH * sizeof(float);   // 8 MB
    const size_t pkBytes = (size_t)NB * NPTS * 4 * sizeof(float);     // 512 KB

    if (ws_size >= ftBytes + pkBytes) {
        float*  featsT = (float*)d_ws;
        float4* packed = (float4*)((char*)d_ws + ftBytes);
        // blocks [0,512): transpose; [512,544): pack points
        prep_kernel<<<544, 256, 0, stream>>>(points, feats, featsT, packed);
        // 4096 centers, 4 per block (one wave each, independent)
        query_group<<<(NB * NCTR) / 4, 256, 0, stream>>>(
            packed, centers, featsT, out_xyz, out_feat);
    } else {
        ballquery_group<<<(NB * NCTR) / 4, 256, 0, stream>>>(
            points, centers, feats, out_xyz, out_feat);
    }
}

// Round 7
// 86.403 us; speedup vs baseline: 1.0218x; 1.0028x over previous
//
#include <hip/hip_runtime.h>
#include <hip/hip_bf16.h>

// Problem constants (fixed shapes from setup_inputs)
constexpr int NPTS = 16384;   // points per batch
constexpr int NCTR = 2048;    // centers per batch
constexpr int NCH  = 64;      // feature channels
constexpr int KK   = 32;      // neighbors per center
constexpr int NB   = 2;       // batches
// radius^2: reference compares d2 < fp32(0.04) (python double 0.2*0.2 -> f32)
#define R2 0.04f

// -------- Kernel A (prep): transpose feats + pack points --------
// blocks [0,512):   transpose features (b,64,16384) -> (b,16384,64) into ws
// blocks [512,544): pack points -> float4 (2x,2y,2z,p2) into ws
// Coords stored DOUBLED: d2 = (c2+p2) - ((2x)cx+(2y)cy+(2z)cz) is bit-equal
// to (c2+p2) - 2*cp because fp rounding commutes with *2^k. p2 uses the
// exact R1-verified formula (contract off) -> selection bit-identical.
__global__ __launch_bounds__(256) void prep_kernel(
    const float* __restrict__ points,   // (2,16384,3)
    const float* __restrict__ feats,    // (2,64,16384)
    float* __restrict__ featsT,         // ws: (2,16384,64)
    float4* __restrict__ packed)        // ws: (2*16384) {2x,2y,2z,p2}
{
#pragma clang fp contract(off)
    __shared__ float tile[64][65];      // +1 pad: conflict-free transpose

    if (blockIdx.x < 512) {
        // ---------------- transpose (cross-wave tile: barrier REQUIRED) ----
        const int b  = blockIdx.x >> 8;
        const int n0 = (blockIdx.x & 255) * 64;
        const int t  = threadIdx.x;
        const int nl = t & 63;
        const int q  = t >> 6;

        const float* fb = feats + (size_t)b * NCH * NPTS;
#pragma unroll
        for (int r = 0; r < 16; ++r) {
            int c = r * 4 + q;
            tile[c][nl] = fb[(size_t)c * NPTS + n0 + nl];
        }
        __syncthreads();
        float* ftb = featsT + ((size_t)b * NPTS + n0) * NCH;
#pragma unroll
        for (int r = 0; r < 16; ++r) {
            int n = r * 4 + q;
            ftb[(size_t)n * NCH + nl] = tile[nl][n];   // 2-way max (free)
        }
        return;
    }

    // ---------------- pack: 32 blocks x 256 thr x 4 pts ----------------
    const int tid = (blockIdx.x - 512) * 256 + threadIdx.x;  // 0..8191
#pragma unroll
    for (int s = 0; s < 4; ++s) {
        const int i = tid + s * 8192;                        // 0..32767 (b*NPTS+n)
        const float x = points[3 * i + 0];
        const float y = points[3 * i + 1];
        const float z = points[3 * i + 2];
        const float p2 = (x * x + y * y) + z * z;            // exact R1 formula
        packed[i] = make_float4(x + x, y + y, z + z, p2);    // doubled (exact)
    }
}

// -------- Kernel B: fused query+group, ONE WAVE = ONE BLOCK per center ----
// R2-R6 all used 4-wave blocks (1024 blocks = one fixed 4-per-CU round):
// a block retires only when its slowest wave does, so CU refill happens at
// block-of-4 granularity and effective occupancy sat at ~4 waves/CU (13%).
// 4096 single-wave blocks (8.8 KB LDS, up to 16/CU) let the dispatcher
// replace each finished center immediately; kernel ends on slowest WAVE.
// Chunk inner loop: 8 independent ballots first, then prefix+writes
// (removes per-sub-iter cnt-chain serialization).
__global__ __launch_bounds__(64, 4) void query_group(
    const float4* __restrict__ packed,  // (2,16384) {2x,2y,2z,p2}
    const float* __restrict__ centers,  // (2,2048,3)
    const float* __restrict__ featsT,   // (2,16384,64)
    float* __restrict__ out_xyz,        // (2,3,2048,32)
    float* __restrict__ out_feat)       // (2,64,2048,32)
{
#pragma clang fp contract(off)          // keep numpy-exact d2 (absmax=0 since R1)
    __shared__ int   idxs[KK];
    __shared__ float sf[KK][68];        // 8.7 KB; rows 16B-aligned for b128

    const int lane = threadIdx.x;       // 0..63 (one wave)
    const int cg   = blockIdx.x;        // 0..4095
    const int b    = cg >> 11;
    const int g    = cg & (NCTR - 1);

    const float4* pk = packed + (size_t)b * NPTS;
    const float* cc = centers + (size_t)cg * 3;
    const float cx = cc[0], cy = cc[1], cz = cc[2];
    const float c2 = (cx * cx + cy * cy) + cz * cz;

    // ---- chunked ballot scan: 512 pts/chunk, next chunk prefetched ----
    float4 cur[8], nxt[8];
#pragma unroll
    for (int j = 0; j < 8; ++j) cur[j] = pk[j * 64 + lane];
    int cnt = 0;
    const unsigned long long lmask = (1ull << lane) - 1ull;
    for (int base = 0; base < NPTS; base += 512) {
        const int nbb = (base + 512 < NPTS) ? base + 512 : 0;
#pragma unroll
        for (int j = 0; j < 8; ++j) nxt[j] = pk[nbb + j * 64 + lane];

        // phase 1: 8 independent ballots (no cnt dependence)
        unsigned long long m[8];
#pragma unroll
        for (int j = 0; j < 8; ++j) {
            const float4 v = cur[j];
            const float cp2 = (cx * v.x + cy * v.y) + cz * v.z;  // == 2*cp exact
            m[j] = __ballot((c2 + v.w) - cp2 < R2);
        }
        // phase 2: prefix across sub-ballots + conditional LDS writes
        int run = cnt;
#pragma unroll
        for (int j = 0; j < 8; ++j) {
            if ((m[j] >> lane) & 1ull) {
                const int slot = run + __popcll(m[j] & lmask);
                if (slot < KK) idxs[slot] = base + j * 64 + lane;
            }
            run += (int)__popcll(m[j]);
        }
        cnt = run;
        if (cnt >= KK) break;                 // wave-uniform
#pragma unroll
        for (int j = 0; j < 8; ++j) cur[j] = nxt[j];
    }
    // single wave: LDS in-order, no barriers anywhere.

    // ---- pad + grouped_xyz ----
    const int cpd = cnt < KK ? cnt : KK;
    const int first = (cnt > 0) ? idxs[0] : 0;
    if (lane < KK) {
        const int id = (lane < cpd) ? idxs[lane] : first;
        idxs[lane] = id;
        const float4 v = pk[id];
        const float px = 0.5f * v.x, py = 0.5f * v.y, pz = 0.5f * v.z;  // exact
        const size_t ob = (((size_t)b * 3 + 0) * NCTR + g) * KK + lane;
        out_xyz[ob + (size_t)0 * NCTR * KK] = (px - cx) / 0.2f;
        out_xyz[ob + (size_t)1 * NCTR * KK] = (py - cy) / 0.2f;
        out_xyz[ob + (size_t)2 * NCTR * KK] = (pz - cz) / 0.2f;
    }

    // ---- gather: 4 rows per b128 instr; 8 instrs cover all 32 rows ----
    const int li = lane & 15, r = lane >> 4;
    const float* ftb = featsT + (size_t)b * NPTS * NCH;
#pragma unroll
    for (int i = 0; i < 8; ++i) {
        const int k = i * 4 + r;
        const float4 v = *((const float4*)(ftb + (size_t)idxs[k] * NCH) + li);
        *(float4*)&sf[k][4 * li] = v;
    }

    // ---- write: lane owns k-quad [4kq,4kq+4) of channel c ----
    // kq=lane&3, c0=lane>>2: LDS read banks (16*(kq&1)+c0)%32 -> 2-way (free)
    const int kq = lane & 3, c0 = lane >> 2;   // c0: 0..15
    const size_t ob = ((size_t)b * NCH * NCTR + g) * KK;
#pragma unroll
    for (int h = 0; h < 2; ++h) {
#pragma unroll
        for (int p = 0; p < 4; ++p) {
            const int c = c0 + 16 * p;
            const int k = 16 * h + 4 * kq;
            float4 w;
            w.x = sf[k + 0][c];
            w.y = sf[k + 1][c];
            w.z = sf[k + 2][c];
            w.w = sf[k + 3][c];
            *(float4*)(out_feat + ob + (size_t)c * NCTR * KK + k) = w;
        }
    }
}

// -------- Fallback: R2 fused kernel (used only if ws is too small) --------
__global__ __launch_bounds__(256) void ballquery_group(
    const float* __restrict__ points, const float* __restrict__ centers,
    const float* __restrict__ feats, float* __restrict__ out_xyz,
    float* __restrict__ out_feat)
{
#pragma clang fp contract(off)
    __shared__ int   s_idx[4][KK];
    __shared__ float s_f[4][KK][65];
    const int wave = threadIdx.x >> 6, lane = threadIdx.x & 63;
    const int cg = blockIdx.x * 4 + wave;
    const int b = cg >> 11, g = cg & (NCTR - 1);
    const float* pb = points + (size_t)b * NPTS * 3;
    const float* cc = centers + (size_t)cg * 3;
    const float cx = cc[0], cy = cc[1], cz = cc[2];
    const float c2 = (cx * cx + cy * cy) + cz * cz;
    int* idxs = s_idx[wave];
    int cnt = 0;
    for (int base = 0; base < NPTS; base += 64) {
        const int i = base + lane;
        const float px = pb[i * 3 + 0], py = pb[i * 3 + 1], pz = pb[i * 3 + 2];
        const float p2 = (px * px + py * py) + pz * pz;
        const float cp = (cx * px + cy * py) + cz * pz;
        const float d2 = (c2 + p2) - 2.0f * cp;
        const bool hit = d2 < R2;
        const unsigned long long m = __ballot(hit);
        if (hit) {
            const int slot = cnt + __popcll(m & ((1ull << lane) - 1ull));
            if (slot < KK) idxs[slot] = i;
        }
        cnt += (int)__popcll(m);
        if (cnt >= KK) break;
    }
    __syncthreads();
    const int cpd = cnt < KK ? cnt : KK;
    const int first = (cnt > 0) ? idxs[0] : 0;
    if (lane < KK) idxs[lane] = (lane < cpd) ? idxs[lane] : first;
    __syncthreads();
    if (lane < KK) {
        const int id = idxs[lane];
        const float px = pb[id * 3 + 0], py = pb[id * 3 + 1], pz = pb[id * 3 + 2];
        const size_t ob = (((size_t)b * 3 + 0) * NCTR + g) * KK + lane;
        out_xyz[ob + (size_t)0 * NCTR * KK] = (px - cx) / 0.2f;
        out_xyz[ob + (size_t)1 * NCTR * KK] = (py - cy) / 0.2f;
        out_xyz[ob + (size_t)2 * NCTR * KK] = (pz - cz) / 0.2f;
    }
    float (*sf)[65] = s_f[wave];
    const float* fb = feats + (size_t)b * NCH * NPTS;
    for (int k = 0; k < KK; ++k) {
        const int id = idxs[k];
        sf[k][lane] = fb[(size_t)lane * NPTS + id];
    }
    __syncthreads();
    const int k = lane & 31, ch = lane >> 5;
    const size_t ob = ((size_t)b * NCH * NCTR + g) * KK;
#pragma unroll
    for (int cc2 = 0; cc2 < 32; ++cc2) {
        const int c = cc2 * 2 + ch;
        out_feat[ob + (size_t)c * NCTR * KK + k] = sf[k][c];
    }
}

extern "C" void kernel_launch(void* const* d_in, const int* in_sizes, int n_in,
                              void* d_out, int out_size, void* d_ws, size_t ws_size,
                              hipStream_t stream) {
    const float* points  = (const float*)d_in[0];   // (2,16384,3)
    const float* centers = (const float*)d_in[1];   // (2,2048,3)
    const float* feats   = (const float*)d_in[2];   // (2,64,16384)

    float* out      = (float*)d_out;
    float* out_xyz  = out;                                    // (2,3,2048,32)
    float* out_feat = out + (size_t)NB * 3 * NCTR * KK;       // (2,64,2048,32)

    const size_t ftBytes = (size_t)NB * NPTS * NCH * sizeof(float);   // 8 MB
    const size_t pkBytes = (size_t)NB * NPTS * 4 * sizeof(float);     // 512 KB

    if (ws_size >= ftBytes + pkBytes) {
        float*  featsT = (float*)d_ws;
        float4* packed = (float4*)((char*)d_ws + ftBytes);
        // blocks [0,512): transpose; [512,544): pack points
        prep_kernel<<<544, 256, 0, stream>>>(points, feats, featsT, packed);
        // one single-wave block per center (4096 blocks of 64 threads)
        query_group<<<NB * NCTR, 64, 0, stream>>>(
            packed, centers, featsT, out_xyz, out_feat);
    } else {
        ballquery_group<<<(NB * NCTR) / 4, 256, 0, stream>>>(
            points, centers, feats, out_xyz, out_feat);
    }
}